// Round 3
// baseline (105.440 us; speedup 1.0000x reference)
//
#include <hip/hip_runtime.h>
#include <hip/hip_cooperative_groups.h>

namespace cg = cooperative_groups;

// RenderingModel: scatter-add of 64x64 filters at N particle positions onto a
// 512x512 canvas (cropped). Gather formulation: each block owns a 32x32 output
// tile AND a 1024-particle segment (grid.z = 8). Phase 1 compacts hits into
// LDS; phase 2 accumulates in registers; segment partials land in per-segment
// planes in d_ws; planes are summed into out.
//
// R6 -> R7: R5 (-45% phase-2 VALU) and R6 (removed ALL 2M global atomics)
// were both NEUTRAL -> render is neither VALU- nor atomic-bound. The data fit
// a different model: R5's tiny build kernel (+0.8us work) cost +8us, R6's
// node-count-neutral swap cost +1us -> EACH GRAPH NODE costs ~7us, and the
// render kernel itself is ~20-25us (likely load/TA-bound: 4 scattered dword
// loads per hit per thread were untouched by R5/R6). R7 attacks both:
//  - ONE node: cooperative launch (2048 blocks x 256 thr = exactly
//    co-resident at launch_bounds(256,8)); render -> planes, grid.sync(),
//    z==0 blocks reduce planes -> out. Memset/reduce nodes deleted.
//  - wave-uniform row-mask skip: per hit, each of the 4 acc-rows' validity is
//    wave-uniform (row is SGPR, a wave spans 2 y values) -> scalar branch
//    skips ~31% of phase-2 loads + ~25% of VALU. Skipped rows contributed
//    exactly 0 -> bitwise-identical output.
// Fallbacks: cooperative-occupancy check -> proven R6 2-node planes path;
// tiny-ws -> proven R4 atomic path.

#define H_  512
#define W_  512
#define FH_ 64
#define FW_ 64
#define TILE_ 32
#define THREADS_ 256
#define SEG_LEN_ 1024            // particles per segment; LDS list sized to this
#define SEGS_    8               // N=8192 -> 8 segments (var path covers rest)
#define PLANE_   (H_ * W_)       // floats per per-segment partial plane

__device__ __forceinline__ int clamp63(int v) {
    return min(max(v, 0), 63);   // -> v_med3_i32
}

// ---- shared core: phase 1 (compact) + phase 2 (accumulate 4 rows/thread) ----
// Returns hit accumulators for pixels (x, ybase + {0,8,16,24}).
__device__ __forceinline__ void render_core(const int* __restrict__ phw,
                                            const float* __restrict__ filters,
                                            int n, unsigned* s_list, int* s_cnt,
                                            float& acc0, float& acc1,
                                            float& acc2, float& acc3) {
    const int t   = threadIdx.x;
    const int tx0 = blockIdx.x * TILE_;
    const int ty0 = blockIdx.y * TILE_;
    const int k0  = blockIdx.z * SEG_LEN_;
    const int k1  = (k0 + SEG_LEN_ < n) ? (k0 + SEG_LEN_) : n;

    if (t == 0) *s_cnt = 0;
    __syncthreads();

    // Phase 1: bbox test + compaction of this segment into LDS.
    for (int k = k0 + t; k < k1; k += THREADS_) {
        const int part = phw[k * 3 + 0];
        const int row  = phw[k * 3 + 1];
        const int col  = phw[k * 3 + 2];
        const bool hit =
            (row >= ty0 - (FH_ / 2 - 1)) && (row <= ty0 + TILE_ - 1 + FH_ / 2) &&
            (col >= tx0 - (FW_ / 2 - 1)) && (col <= tx0 + TILE_ - 1 + FW_ / 2);
        if (hit) {
            const int idx = atomicAdd(s_cnt, 1);
            // pack: part(8b) | row(9b) | col(9b)
            s_list[idx] = ((unsigned)part << 18) | ((unsigned)row << 9) | (unsigned)col;
        }
    }
    __syncthreads();
    const int cnt = *s_cnt;

    // Phase 2. Thread t owns (x = tx0+(t&31), y = ty0+(t>>5)+8q), q=0..3.
    const int xl    = t & 31;
    const int yb    = t >> 5;              // 0..7
    const int x     = tx0 + xl;
    const int ybase = ty0 + yb;
    // Wave-uniform row base: lanes of one wave have yb in {ybw, ybw+1}.
    const int ybw   = (int)__builtin_amdgcn_readfirstlane(yb);

    acc0 = 0.f; acc1 = 0.f; acc2 = 0.f; acc3 = 0.f;

    auto body = [&](unsigned v) {
        const int part = (int)__builtin_amdgcn_readfirstlane(v >> 18);
        const int row  = (int)__builtin_amdgcn_readfirstlane((v >> 9) & 511u);
        const int col  = (int)__builtin_amdgcn_readfirstlane(v & 511u);
        const float* __restrict__ f = filters + (part << 12);  // SGPR base

        const int  j   = x - col + (FW_ / 2);
        const int  jc  = clamp63(j);
        const bool jok = (unsigned)j < (unsigned)FW_;
        const int  i0  = ybase - row + (FH_ / 2);
        // Wave-uniform: i0 for this wave's lanes is A or A+1. Row q live iff
        // A+8q in [-1, 63]; otherwise no lane has a valid row -> scalar skip.
        const int  A   = ty0 + ybw - row + (FH_ / 2);

        if (A >=  -1 && A <= 63) {                       // q=0
            const float va = f[clamp63(i0) * FW_ + jc];
            acc0 += (jok && (unsigned)i0 < (unsigned)FH_) ? va : 0.f;
        }
        if (A >=  -9 && A <= 55) {                       // q=1
            const int ib = i0 + 8;
            const float vb = f[clamp63(ib) * FW_ + jc];
            acc1 += (jok && (unsigned)ib < (unsigned)FH_) ? vb : 0.f;
        }
        if (A >= -17 && A <= 47) {                       // q=2
            const int ic = i0 + 16;
            const float vc = f[clamp63(ic) * FW_ + jc];
            acc2 += (jok && (unsigned)ic < (unsigned)FH_) ? vc : 0.f;
        }
        if (A >= -25 && A <= 39) {                       // q=3
            const int id = i0 + 24;
            const float vd = f[clamp63(id) * FW_ + jc];
            acc3 += (jok && (unsigned)id < (unsigned)FH_) ? vd : 0.f;
        }
    };

    int k = 0;
    for (; k + 4 <= cnt; k += 4) {
        // 4 wave-uniform entries in one 16B LDS read (k%4==0 -> aligned)
        const uint4 vv = *(const uint4*)&s_list[k];
        body(vv.x); body(vv.y); body(vv.z); body(vv.w);
    }
    for (; k < cnt; ++k) body(s_list[k]);
}

// ---- R7 single-node cooperative kernel: render -> planes, sync, reduce ----
__global__ __launch_bounds__(THREADS_, 8)
void render_coop(const int* __restrict__ phw, const float* __restrict__ filters,
                 float* __restrict__ planes, float* __restrict__ out, int n) {
    __shared__ unsigned s_list[SEG_LEN_];
    __shared__ int s_cnt;

    float a0, a1, a2, a3;
    render_core(phw, filters, n, s_list, &s_cnt, a0, a1, a2, a3);

    const int t     = threadIdx.x;
    const int x     = blockIdx.x * TILE_ + (t & 31);
    const int ybase = blockIdx.y * TILE_ + (t >> 5);
    float* __restrict__ plane = planes + (size_t)blockIdx.z * PLANE_;
    plane[(ybase +  0) * W_ + x] = a0;
    plane[(ybase +  8) * W_ + x] = a1;
    plane[(ybase + 16) * W_ + x] = a2;
    plane[(ybase + 24) * W_ + x] = a3;

    __threadfence();                 // release partials (device scope)
    cg::this_grid().sync();          // grid-wide barrier + memory ordering

    // Reduce: z==0 blocks (256 of them) sum SEGS_ planes, one float4/thread.
    if (blockIdx.z == 0) {
        const int i = (((int)blockIdx.y * (int)gridDim.x + (int)blockIdx.x) * THREADS_ + t) * 4;
        float4 a = *(const float4*)&planes[i];
#pragma unroll
        for (int s = 1; s < SEGS_; ++s) {
            const float4 b = *(const float4*)&planes[(size_t)s * PLANE_ + i];
            a.x += b.x; a.y += b.y; a.z += b.z; a.w += b.w;
        }
        *(float4*)&out[i] = a;
    }
}

// ---- fallback kernels (proven R6/R4 paths) ----
template<bool PLANES>
__global__ __launch_bounds__(THREADS_, 8)
void render_tile_kernel(const int* __restrict__ phw,
                        const float* __restrict__ filters,
                        float* __restrict__ dst, int n) {
    __shared__ unsigned s_list[SEG_LEN_];
    __shared__ int s_cnt;

    float a0, a1, a2, a3;
    render_core(phw, filters, n, s_list, &s_cnt, a0, a1, a2, a3);

    const int t     = threadIdx.x;
    const int x     = blockIdx.x * TILE_ + (t & 31);
    const int ybase = blockIdx.y * TILE_ + (t >> 5);

    if constexpr (PLANES) {
        float* __restrict__ plane = dst + (size_t)blockIdx.z * PLANE_;
        plane[(ybase +  0) * W_ + x] = a0;
        plane[(ybase +  8) * W_ + x] = a1;
        plane[(ybase + 16) * W_ + x] = a2;
        plane[(ybase + 24) * W_ + x] = a3;
    } else {
        atomicAdd(&dst[(ybase +  0) * W_ + x], a0);
        atomicAdd(&dst[(ybase +  8) * W_ + x], a1);
        atomicAdd(&dst[(ybase + 16) * W_ + x], a2);
        atomicAdd(&dst[(ybase + 24) * W_ + x], a3);
    }
}

__global__ __launch_bounds__(256)
void reduce_planes_var(const float* __restrict__ planes, float* __restrict__ out,
                       int segs) {
    const int i = (blockIdx.x * 256 + threadIdx.x) * 4;
    float4 a = *(const float4*)&planes[i];
    for (int s = 1; s < segs; ++s) {
        const float4 b = *(const float4*)&planes[(size_t)s * PLANE_ + i];
        a.x += b.x; a.y += b.y; a.z += b.z; a.w += b.w;
    }
    *(float4*)&out[i] = a;
}

extern "C" void kernel_launch(void* const* d_in, const int* in_sizes, int n_in,
                              void* d_out, int out_size, void* d_ws, size_t ws_size,
                              hipStream_t stream) {
    const int*   phw     = (const int*)d_in[0];
    const float* filters = (const float*)d_in[1];
    float*       out     = (float*)d_out;
    const int n = in_sizes[0] / 3;

    if (n <= 0) {
        hipMemsetAsync(out, 0, (size_t)H_ * W_ * sizeof(float), stream);
        return;
    }

    const int segs = (n + SEG_LEN_ - 1) / SEG_LEN_;
    const size_t plane_bytes = (size_t)segs * PLANE_ * sizeof(float);
    dim3 grid(W_ / TILE_, H_ / TILE_, segs);

    // One-time cooperative-capacity check (pure queries, capture-safe).
    static int coop_ok = -1;
    if (coop_ok < 0) {
        int blocksPerCU = 0, numCU = 0;
        hipError_t e1 = hipOccupancyMaxActiveBlocksPerMultiprocessor(
            &blocksPerCU, (const void*)render_coop, THREADS_, 0);
        hipDeviceProp_t prop;
        hipError_t e2 = hipGetDeviceProperties(&prop, 0);
        numCU = prop.multiProcessorCount;
        coop_ok = (e1 == hipSuccess && e2 == hipSuccess &&
                   (long)blocksPerCU * numCU >= (long)grid.x * grid.y * SEGS_) ? 1 : 0;
    }

    if (d_ws != nullptr && ws_size >= plane_bytes && segs == SEGS_ && coop_ok == 1) {
        // Single-node path: render + grid.sync + reduce in one kernel.
        float* planes = (float*)d_ws;
        void* args[] = {(void*)&phw, (void*)&filters, (void*)&planes,
                        (void*)&out, (void*)&n};
        hipLaunchCooperativeKernel((const void*)render_coop, grid,
                                   dim3(THREADS_), args, 0, stream);
    } else if (d_ws != nullptr && ws_size >= plane_bytes) {
        // R6 fallback: 2-node planes + reduce.
        float* planes = (float*)d_ws;
        render_tile_kernel<true><<<grid, dim3(THREADS_), 0, stream>>>(
            phw, filters, planes, n);
        const int rblocks = PLANE_ / 4 / 256;   // 256
        reduce_planes_var<<<dim3(rblocks), dim3(256), 0, stream>>>(planes, out, segs);
    } else {
        // R4 fallback: zero out, render with device atomics.
        hipMemsetAsync(out, 0, (size_t)H_ * W_ * sizeof(float), stream);
        render_tile_kernel<false><<<grid, dim3(THREADS_), 0, stream>>>(
            phw, filters, out, n);
    }
}

// Round 4
// 86.068 us; speedup vs baseline: 1.2251x; 1.2251x over previous
//
#include <hip/hip_runtime.h>

// RenderingModel: scatter-add of 64x64 filters at N particle positions onto a
// 512x512 canvas (cropped). Gather formulation: each block owns a 32x32 output
// tile AND a 1024-particle segment (grid.z = 8). Phase 1 compacts hits into
// LDS; phase 2 accumulates in registers; per-segment partial planes in d_ws;
// reduce kernel sums planes -> out.
//
// History: R5 (-45% phase-2 VALU via padded filters) NEUTRAL; R6 (removed all
// 2M global atomics -> planes+reduce) NEUTRAL; R7 (single-node cooperative)
// BIG REGRESSION (grid.sync ~ +23us) but produced the first real counters on
// the render kernel: VALU-busy ~15us, FETCH 22MB (~3.5us BW), conflicts 0,
// occupancy 95%, VGPR_Count = 20. Render is ~36us with ~15us of issue ->
// ~60% of its time is UNHIDDEN LOAD LATENCY: at 20 VGPRs the compiler holds
// only one 4-load body in flight (tight vmcnt per body), serializing each
// wave on ~200-400cy L2/L3 filter loads.
//
// R7 -> R8: revert to the proven R6 2-node structure; rewrite phase 2 as an
// explicit 2-deep software pipeline at uint4-group granularity: issue group
// k+1's 16 loads BEFORE consuming group k's values (32 dwords in flight per
// wave; all array indexing under #pragma unroll = compile-time, no scratch).
// launch_bounds relaxed to (256,4): VGPR cap 128 (no spill risk), 16 waves/CU
// of TLP — 95% occupancy demonstrably wasn't the limiter. Same adds in the
// same order -> bitwise-identical output.

#define H_  512
#define W_  512
#define FH_ 64
#define FW_ 64
#define TILE_ 32
#define THREADS_ 256
#define SEG_LEN_ 1024            // particles per segment; LDS list sized to this
#define PLANE_   (H_ * W_)       // floats per per-segment partial plane

__device__ __forceinline__ int clamp63(int v) {
    return min(max(v, 0), 63);   // -> v_med3_i32
}

// In-flight state for 4 hits x 4 rows: 16 loaded floats + per-hit validity.
struct Batch {
    float p0[4], p1[4], p2[4], p3[4];   // p{q}[e]: row q of entry e
    int   i0[4];                        // row base per entry (per-lane)
    int   jok[4];                       // col-valid per entry (per-lane, 0/1)
};

// Issue one group's 16 loads (branchless clamped addresses: loads always
// valid; selection deferred to consume). Entries are wave-uniform ->
// readfirstlane puts part/row/col in SGPRs; loads are SGPR-base + offset.
__device__ __forceinline__ Batch issue_batch(const float* __restrict__ filters,
                                             uint4 vv, int x, int ybase) {
    Batch b;
    const unsigned ev[4] = {vv.x, vv.y, vv.z, vv.w};
#pragma unroll
    for (int e = 0; e < 4; ++e) {
        const unsigned v = ev[e];
        const int part = (int)__builtin_amdgcn_readfirstlane(v >> 18);
        const int row  = (int)__builtin_amdgcn_readfirstlane((v >> 9) & 511u);
        const int col  = (int)__builtin_amdgcn_readfirstlane(v & 511u);
        const float* __restrict__ f = filters + (part << 12);  // SGPR base

        const int j  = x - col + (FW_ / 2);
        const int jc = clamp63(j);
        const int i0 = ybase - row + (FH_ / 2);
        b.jok[e] = (unsigned)j < (unsigned)FW_;
        b.i0[e]  = i0;
        b.p0[e] = f[clamp63(i0     ) * FW_ + jc];
        b.p1[e] = f[clamp63(i0 +  8) * FW_ + jc];
        b.p2[e] = f[clamp63(i0 + 16) * FW_ + jc];
        b.p3[e] = f[clamp63(i0 + 24) * FW_ + jc];
    }
    return b;
}

// Fold one batch into the accumulators (value select kills out-of-range).
__device__ __forceinline__ void consume_batch(const Batch& b, float& a0,
                                              float& a1, float& a2, float& a3) {
#pragma unroll
    for (int e = 0; e < 4; ++e) {
        const int  i0  = b.i0[e];
        const bool jok = b.jok[e] != 0;
        a0 += (jok && (unsigned)(i0     ) < (unsigned)FH_) ? b.p0[e] : 0.f;
        a1 += (jok && (unsigned)(i0 +  8) < (unsigned)FH_) ? b.p1[e] : 0.f;
        a2 += (jok && (unsigned)(i0 + 16) < (unsigned)FH_) ? b.p2[e] : 0.f;
        a3 += (jok && (unsigned)(i0 + 24) < (unsigned)FH_) ? b.p3[e] : 0.f;
    }
}

// ---- shared core: phase 1 (compact) + phase 2 (pipelined accumulate) ----
__device__ __forceinline__ void render_core(const int* __restrict__ phw,
                                            const float* __restrict__ filters,
                                            int n, unsigned* s_list, int* s_cnt,
                                            float& acc0, float& acc1,
                                            float& acc2, float& acc3) {
    const int t   = threadIdx.x;
    const int tx0 = blockIdx.x * TILE_;
    const int ty0 = blockIdx.y * TILE_;
    const int k0  = blockIdx.z * SEG_LEN_;
    const int k1  = (k0 + SEG_LEN_ < n) ? (k0 + SEG_LEN_) : n;

    if (t == 0) *s_cnt = 0;
    __syncthreads();

    // Phase 1: bbox test + compaction of this segment into LDS.
    for (int k = k0 + t; k < k1; k += THREADS_) {
        const int part = phw[k * 3 + 0];
        const int row  = phw[k * 3 + 1];
        const int col  = phw[k * 3 + 2];
        const bool hit =
            (row >= ty0 - (FH_ / 2 - 1)) && (row <= ty0 + TILE_ - 1 + FH_ / 2) &&
            (col >= tx0 - (FW_ / 2 - 1)) && (col <= tx0 + TILE_ - 1 + FW_ / 2);
        if (hit) {
            const int idx = atomicAdd(s_cnt, 1);
            // pack: part(8b) | row(9b) | col(9b)
            s_list[idx] = ((unsigned)part << 18) | ((unsigned)row << 9) | (unsigned)col;
        }
    }
    __syncthreads();
    const int cnt = *s_cnt;

    // Phase 2. Thread t owns (x = tx0+(t&31), y = ty0+(t>>5)+8q), q=0..3.
    const int x     = tx0 + (t & 31);
    const int ybase = ty0 + (t >> 5);

    acc0 = 0.f; acc1 = 0.f; acc2 = 0.f; acc3 = 0.f;

    // 2-deep pipeline over aligned uint4 groups: issue group g+1's 16 loads
    // before consuming group g (32 dwords outstanding per wave).
    int k = 0;
    if (cnt >= 4) {
        Batch A = issue_batch(filters, *(const uint4*)&s_list[0], x, ybase);
        for (k = 4; k + 4 <= cnt; k += 4) {
            const Batch B = issue_batch(filters, *(const uint4*)&s_list[k], x, ybase);
            consume_batch(A, acc0, acc1, acc2, acc3);
            A = B;
        }
        consume_batch(A, acc0, acc1, acc2, acc3);
    }
    // Tail (<4 entries): simple single-entry bodies, same math and order.
    for (; k < cnt; ++k) {
        const unsigned v = s_list[k];
        const int part = (int)__builtin_amdgcn_readfirstlane(v >> 18);
        const int row  = (int)__builtin_amdgcn_readfirstlane((v >> 9) & 511u);
        const int col  = (int)__builtin_amdgcn_readfirstlane(v & 511u);
        const float* __restrict__ f = filters + (part << 12);

        const int  j   = x - col + (FW_ / 2);
        const int  jc  = clamp63(j);
        const bool jok = (unsigned)j < (unsigned)FW_;
        const int  i0  = ybase - row + (FH_ / 2);
        const float va = f[clamp63(i0     ) * FW_ + jc];
        const float vb = f[clamp63(i0 +  8) * FW_ + jc];
        const float vc = f[clamp63(i0 + 16) * FW_ + jc];
        const float vd = f[clamp63(i0 + 24) * FW_ + jc];
        acc0 += (jok && (unsigned)(i0     ) < (unsigned)FH_) ? va : 0.f;
        acc1 += (jok && (unsigned)(i0 +  8) < (unsigned)FH_) ? vb : 0.f;
        acc2 += (jok && (unsigned)(i0 + 16) < (unsigned)FH_) ? vc : 0.f;
        acc3 += (jok && (unsigned)(i0 + 24) < (unsigned)FH_) ? vd : 0.f;
    }
}

// ---- render kernels ----
template<bool PLANES>
__global__ __launch_bounds__(THREADS_, 4)   // VGPR cap 128: room for pipeline
void render_tile_kernel(const int* __restrict__ phw,
                        const float* __restrict__ filters,
                        float* __restrict__ dst, int n) {
    __shared__ unsigned s_list[SEG_LEN_];
    __shared__ int s_cnt;

    float a0, a1, a2, a3;
    render_core(phw, filters, n, s_list, &s_cnt, a0, a1, a2, a3);

    const int t     = threadIdx.x;
    const int x     = blockIdx.x * TILE_ + (t & 31);
    const int ybase = blockIdx.y * TILE_ + (t >> 5);

    if constexpr (PLANES) {
        // Private per-segment plane: disjoint plain stores, no RMW.
        float* __restrict__ plane = dst + (size_t)blockIdx.z * PLANE_;
        plane[(ybase +  0) * W_ + x] = a0;
        plane[(ybase +  8) * W_ + x] = a1;
        plane[(ybase + 16) * W_ + x] = a2;
        plane[(ybase + 24) * W_ + x] = a3;
    } else {
        // Fallback: combine segments via device atomics (dst pre-zeroed).
        atomicAdd(&dst[(ybase +  0) * W_ + x], a0);
        atomicAdd(&dst[(ybase +  8) * W_ + x], a1);
        atomicAdd(&dst[(ybase + 16) * W_ + x], a2);
        atomicAdd(&dst[(ybase + 24) * W_ + x], a3);
    }
}

// Sum per-segment planes into out; every output pixel written (no memset
// needed). Fixed-order adds -> deterministic.
template<int SEGS>
__global__ __launch_bounds__(256)
void reduce_planes_fixed(const float* __restrict__ planes, float* __restrict__ out) {
    const int i = (blockIdx.x * 256 + threadIdx.x) * 4;
    float4 a = *(const float4*)&planes[i];
#pragma unroll
    for (int s = 1; s < SEGS; ++s) {
        const float4 b = *(const float4*)&planes[(size_t)s * PLANE_ + i];
        a.x += b.x; a.y += b.y; a.z += b.z; a.w += b.w;
    }
    *(float4*)&out[i] = a;
}

__global__ __launch_bounds__(256)
void reduce_planes_var(const float* __restrict__ planes, float* __restrict__ out,
                       int segs) {
    const int i = (blockIdx.x * 256 + threadIdx.x) * 4;
    float4 a = *(const float4*)&planes[i];
    for (int s = 1; s < segs; ++s) {
        const float4 b = *(const float4*)&planes[(size_t)s * PLANE_ + i];
        a.x += b.x; a.y += b.y; a.z += b.z; a.w += b.w;
    }
    *(float4*)&out[i] = a;
}

extern "C" void kernel_launch(void* const* d_in, const int* in_sizes, int n_in,
                              void* d_out, int out_size, void* d_ws, size_t ws_size,
                              hipStream_t stream) {
    const int*   phw     = (const int*)d_in[0];
    const float* filters = (const float*)d_in[1];
    float*       out     = (float*)d_out;
    const int n = in_sizes[0] / 3;

    if (n <= 0) {
        hipMemsetAsync(out, 0, (size_t)H_ * W_ * sizeof(float), stream);
        return;
    }

    const int segs = (n + SEG_LEN_ - 1) / SEG_LEN_;
    const size_t plane_bytes = (size_t)segs * PLANE_ * sizeof(float);
    dim3 grid(W_ / TILE_, H_ / TILE_, segs);

    if (d_ws != nullptr && ws_size >= plane_bytes) {
        // Atomic-free path: render partial planes into ws (fully overwritten
        // every call -> safe against ws re-poison), then reduce.
        float* planes = (float*)d_ws;
        render_tile_kernel<true><<<grid, dim3(THREADS_), 0, stream>>>(
            phw, filters, planes, n);
        const int rblocks = PLANE_ / 4 / 256;   // 256
        if (segs == 8) {
            reduce_planes_fixed<8><<<dim3(rblocks), dim3(256), 0, stream>>>(planes, out);
        } else {
            reduce_planes_var<<<dim3(rblocks), dim3(256), 0, stream>>>(planes, out, segs);
        }
    } else {
        // Proven fallback: zero out, render with device atomics.
        hipMemsetAsync(out, 0, (size_t)H_ * W_ * sizeof(float), stream);
        render_tile_kernel<false><<<grid, dim3(THREADS_), 0, stream>>>(
            phw, filters, out, n);
    }
}